// Round 1
// 1421.984 us; speedup vs baseline: 1.1429x; 1.1429x over previous
//
#include <hip/hip_runtime.h>
#include <stdint.h>

#define AS1 __attribute__((address_space(1)))
#define AS3 __attribute__((address_space(3)))

typedef unsigned short u16;
typedef __attribute__((ext_vector_type(8))) short s16x8;
typedef __attribute__((ext_vector_type(8))) unsigned short u16x8;
typedef __attribute__((ext_vector_type(4))) float f32x4;

__device__ __forceinline__ u16 f2bf(float f) {
    union { float f; unsigned int u; } v; v.f = f;
    unsigned int r = v.u + 0x7fffu + ((v.u >> 16) & 1u);
    return (u16)(r >> 16);
}

// async global->LDS, 16B per lane. LDS dest = wave-uniform base + lane*16.
__device__ __forceinline__ void gld_lds16(const u16* g, u16* l) {
    __builtin_amdgcn_global_load_lds((AS1 unsigned int*)(uintptr_t)g,
                                     (AS3 unsigned int*)(uintptr_t)l, 16, 0, 0);
}

// ---------------- convert x: fp32 -> bf16 ----------------
__global__ void convert_x_kernel(const float* __restrict__ X, u16* __restrict__ Xb, int total8) {
    int i = blockIdx.x * 256 + threadIdx.x;
    if (i < total8) {
        f32x4 a = ((const f32x4*)X)[2 * i];
        f32x4 b = ((const f32x4*)X)[2 * i + 1];
        u16x8 o;
#pragma unroll
        for (int j = 0; j < 4; j++) { o[j] = f2bf(a[j]); o[4 + j] = f2bf(b[j]); }
        ((u16x8*)Xb)[i] = o;
    }
}

// ---------------- gating: gates[n][50] = softmax(x@Wg + bg), all fp32 ----------------
__global__ void gate_kernel(const float* __restrict__ X, const float* __restrict__ Wg,
                            const float* __restrict__ bg, float* __restrict__ gates, int nt) {
    __shared__ float xs[1024];
    const int n = blockIdx.x;
    const int t = threadIdx.x; // 64 threads = 1 wave
#pragma unroll
    for (int i = 0; i < 16; i++) xs[t + i * 64] = X[(size_t)n * 1024 + t + i * 64];
    __syncthreads();
    float a = -INFINITY;
    if (t < 50) {
        float s0 = 0.f, s1 = 0.f, s2 = 0.f, s3 = 0.f;
        for (int d = 0; d < 1024; d += 4) {
            s0 += xs[d + 0] * Wg[(d + 0) * 50 + t];
            s1 += xs[d + 1] * Wg[(d + 1) * 50 + t];
            s2 += xs[d + 2] * Wg[(d + 2) * 50 + t];
            s3 += xs[d + 3] * Wg[(d + 3) * 50 + t];
        }
        a = (s0 + s1) + (s2 + s3) + bg[t];
    }
    float m = a;
#pragma unroll
    for (int off = 32; off > 0; off >>= 1) m = fmaxf(m, __shfl_xor(m, off));
    float p = (t < 50) ? __expf(a - m) : 0.f;
    float ss = p;
#pragma unroll
    for (int off = 32; off > 0; off >>= 1) ss += __shfl_xor(ss, off);
    if (t < 50) gates[(size_t)n * 50 + t] = p / ss;
}

// ------- transpose+convert 1024x1024 fp32 [k][n] -> bf16 [n][k]; z: eg W1 mats then eg W2 mats ----
__global__ void transpose_kernel(const float* __restrict__ W1s, const float* __restrict__ W2s,
                                 u16* __restrict__ Wt1, u16* __restrict__ Wt2, int eg) {
    __shared__ u16 tile[64 * 65];
    const int t = threadIdx.x; // 256
    const int z = blockIdx.z;
    const float* src; u16* dst;
    if (z < eg) { src = W1s + ((size_t)z << 20); dst = Wt1 + ((size_t)z << 20); }
    else        { src = W2s + ((size_t)(z - eg) << 20); dst = Wt2 + ((size_t)(z - eg) << 20); }
    const int k0 = blockIdx.y * 64;
    const int n0 = blockIdx.x * 64;
#pragma unroll
    for (int p = 0; p < 4; p++) {
        int r = (t >> 4) + 16 * p;
        int c = t & 15;
        f32x4 v = *(const f32x4*)(src + (size_t)(k0 + r) * 1024 + n0 + c * 4);
#pragma unroll
        for (int j = 0; j < 4; j++) tile[r * 65 + c * 4 + j] = f2bf(v[j]);
    }
    __syncthreads();
#pragma unroll
    for (int p = 0; p < 2; p++) {
        int h = (t >> 3) + 32 * p;
        int c = t & 7;
        u16x8 o;
#pragma unroll
        for (int j = 0; j < 8; j++) o[j] = tile[(c * 8 + j) * 65 + h];
        *(u16x8*)(dst + (size_t)(n0 + h) * 1024 + k0 + c * 8) = o;
    }
}

// =====================================================================================
// 256x256-tile pipelined GEMMs: BK=32, 4 LDS buffers, prefetch distance 3,
// counted vmcnt (8 -> 4 -> 0), one s_barrier per K-tile, setprio around MFMA cluster.
// 8 waves (512 thr), wave grid 2m x 4n, per-wave output 128x64 (acc 8x4 f32x4).
// LDS swizzle: both-sides XOR (pre-swizzled global source + XOR'd ds_read offset),
// chunk = (lane&3) ^ (row&3) on 64B rows.
// =====================================================================================

#define BUF_U16 16384  // per buffer: A 8192 u16 (256x32) + B 8192 u16 (256x32) = 32KB

#define STG1(t) { int bo = ((t) & 3) * BUF_U16;                                   \
        const u16* a = Ag + (t) * 32; const u16* b = Bg + (t) * 32;               \
        gld_lds16(a, Ald + bo);          gld_lds16(a + 131072, Ald + bo + 4096);  \
        gld_lds16(b, Bld + bo);          gld_lds16(b + 131072, Bld + bo + 4096); }

#define STG2(t) { int kt = kb + (t) * 32; int ee = kt >> 10; int kk = kt & 1023;  \
        const u16* a = Agr + (size_t)ee * ntk + kk;                               \
        const u16* b = Bgr + ((size_t)ee << 20) + kk;                             \
        int bo = ((t) & 3) * BUF_U16;                                             \
        gld_lds16(a, Ald + bo);          gld_lds16(a + 131072, Ald + bo + 4096);  \
        gld_lds16(b, Bld + bo);          gld_lds16(b + 131072, Bld + bo + 4096); }

#define MMSTEP(t, VM, DO, STG) {                                                  \
        asm volatile("s_waitcnt vmcnt(" VM ")\n\ts_barrier" ::: "memory");        \
        if (DO) STG((t) + 3);                                                     \
        const u16* bp = smem + ((t) & 3) * BUF_U16;                               \
        s16x8 av[8], bv[4];                                                       \
        _Pragma("unroll") for (int mi = 0; mi < 8; mi++)                          \
            av[mi] = *(const s16x8*)(bp + aoff[mi]);                              \
        _Pragma("unroll") for (int nj = 0; nj < 4; nj++)                          \
            bv[nj] = *(const s16x8*)(bp + boff[nj]);                              \
        __builtin_amdgcn_s_setprio(1);                                            \
        _Pragma("unroll") for (int mi = 0; mi < 8; mi++)                          \
        _Pragma("unroll") for (int nj = 0; nj < 4; nj++)                          \
            acc[mi * 4 + nj] = __builtin_amdgcn_mfma_f32_16x16x32_bf16(           \
                av[mi], bv[nj], acc[mi * 4 + nj], 0, 0, 0);                       \
        __builtin_amdgcn_s_setprio(0); }

// ---------------- gemm1: Hp[e] = bf16( gates[:,e] * relu(Xb @ W1t[e] + b1[e]) ) ----------
__global__ __launch_bounds__(512, 2)
void gemm1_kernel(const u16* __restrict__ X, const u16* __restrict__ Wt1,
                  const float* __restrict__ b1, const float* __restrict__ gates,
                  u16* __restrict__ Hp, int nt, int egbase) {
    __shared__ __align__(16) u16 smem[67584]; // 4 bufs (128KB) / C-tile 256x264 (135KB)
    const int tid = threadIdx.x, wave = tid >> 6, lane = tid & 63;
    const int e = blockIdx.z;
    const int n0 = blockIdx.x * 256, m0 = blockIdx.y * 256;

    // staging: thread covers row srow (call0) / srow+128 (call1), 16B chunk, pre-swizzled source
    const int srow = wave * 16 + (lane >> 2);
    const int scg = ((lane & 3) ^ (srow & 3)) * 8;
    const u16* Ag = X + (size_t)(m0 + srow) * 1024 + scg;
    const u16* Bg = Wt1 + ((size_t)e << 20) + (size_t)(n0 + srow) * 1024 + scg;
    u16* Ald = smem + wave * 512;
    u16* Bld = smem + 8192 + wave * 512;

    const int wm = wave >> 2, wn = wave & 3;
    const int fr = lane & 15, fq = lane >> 4;
    int aoff[8], boff[4];
#pragma unroll
    for (int mi = 0; mi < 8; mi++) {
        int ra = wm * 128 + mi * 16 + fr;
        aoff[mi] = ra * 32 + ((fq ^ (ra & 3)) * 8);
    }
#pragma unroll
    for (int nj = 0; nj < 4; nj++) {
        int rb = wn * 64 + nj * 16 + fr;
        boff[nj] = 8192 + rb * 32 + ((fq ^ (rb & 3)) * 8);
    }

    f32x4 acc[32];
#pragma unroll
    for (int i = 0; i < 32; i++) acc[i] = (f32x4){0.f, 0.f, 0.f, 0.f};

    STG1(0); STG1(1); STG1(2);
    for (int t = 0; t < 29; ++t) MMSTEP(t, "8", 1, STG1);
    MMSTEP(29, "8", 0, STG1);
    MMSTEP(30, "4", 0, STG1);
    MMSTEP(31, "0", 0, STG1);

    // epilogue: bias + relu + gate, bounce through LDS for coalesced bf16 stores
    const float* b1e = b1 + (size_t)e * 1024;
    float b1v[4];
#pragma unroll
    for (int nj = 0; nj < 4; nj++) b1v[nj] = b1e[n0 + wn * 64 + nj * 16 + fr];
    const int eglob = egbase + e;

    __syncthreads(); // all waves done reading bufs; reuse smem as C tile (stride 264)
#pragma unroll
    for (int mi = 0; mi < 8; mi++) {
#pragma unroll
        for (int ri = 0; ri < 4; ri++) {
            int row = wm * 128 + mi * 16 + fq * 4 + ri;
            float g = gates[(size_t)(m0 + row) * 50 + eglob];
#pragma unroll
            for (int nj = 0; nj < 4; nj++) {
                int col = wn * 64 + nj * 16 + fr;
                float h = acc[mi * 4 + nj][ri] + b1v[nj];
                h = h > 0.f ? h * g : 0.f;
                smem[row * 264 + col] = f2bf(h);
            }
        }
    }
    __syncthreads();
    u16* HpE = Hp + (size_t)e * nt * 1024;
    const int c = tid & 31, rr = tid >> 5;
#pragma unroll
    for (int p = 0; p < 16; p++) {
        int r = rr + p * 16;
        u16x8 v = *(const u16x8*)(smem + r * 264 + c * 8);
        *(u16x8*)(HpE + (size_t)(m0 + r) * 1024 + n0 + c * 8) = v;
    }
}

// ---------------- gemm2: partial[s] (+)= slice_s( sum_e Hp[e] @ W2t[e] ), s in 0..3 ----------
__global__ __launch_bounds__(512, 2)
void gemm2_kernel(const u16* __restrict__ Hp, const u16* __restrict__ Wt2,
                  float* __restrict__ partial, int nt, int eg, int init) {
    __shared__ __align__(16) u16 smem[65536]; // 4 bufs = 128KB
    const int tid = threadIdx.x, wave = tid >> 6, lane = tid & 63;
    const int s = blockIdx.z;
    const int n0 = blockIdx.x * 256, m0 = blockIdx.y * 256;

    const int srow = wave * 16 + (lane >> 2);
    const int scg = ((lane & 3) ^ (srow & 3)) * 8;
    const u16* Agr = Hp + (size_t)(m0 + srow) * 1024 + scg;
    const u16* Bgr = Wt2 + (size_t)(n0 + srow) * 1024 + scg;
    const size_t ntk = (size_t)nt * 1024;
    u16* Ald = smem + wave * 512;
    u16* Bld = smem + 8192 + wave * 512;

    const int wm = wave >> 2, wn = wave & 3;
    const int fr = lane & 15, fq = lane >> 4;
    int aoff[8], boff[4];
#pragma unroll
    for (int mi = 0; mi < 8; mi++) {
        int ra = wm * 128 + mi * 16 + fr;
        aoff[mi] = ra * 32 + ((fq ^ (ra & 3)) * 8);
    }
#pragma unroll
    for (int nj = 0; nj < 4; nj++) {
        int rb = wn * 64 + nj * 16 + fr;
        boff[nj] = 8192 + rb * 32 + ((fq ^ (rb & 3)) * 8);
    }

    f32x4 acc[32];
#pragma unroll
    for (int i = 0; i < 32; i++) acc[i] = (f32x4){0.f, 0.f, 0.f, 0.f};

    const int NT = eg * 8;       // K-tiles of 32 in this slice (eg*1024/4/32)
    const int kb = s * NT * 32;  // absolute k start of slice

    STG2(0); STG2(1); STG2(2);
    for (int t = 0; t < NT - 3; ++t) MMSTEP(t, "8", 1, STG2);
    MMSTEP(NT - 3, "8", 0, STG2);
    MMSTEP(NT - 2, "4", 0, STG2);
    MMSTEP(NT - 1, "0", 0, STG2);

    float* pp = partial + (size_t)s * nt * 1024;
#pragma unroll
    for (int mi = 0; mi < 8; mi++) {
#pragma unroll
        for (int ri = 0; ri < 4; ri++) {
            int gr = m0 + wm * 128 + mi * 16 + fq * 4 + ri;
#pragma unroll
            for (int nj = 0; nj < 4; nj++) {
                size_t idx = (size_t)gr * 1024 + n0 + wn * 64 + nj * 16 + fr;
                float v = acc[mi * 4 + nj][ri];
                if (!init) v += pp[idx];
                pp[idx] = v;
            }
        }
    }
}

// ---------------- finalize: out = sum_s partial[s] + sum_e gates*b2, fp32 out ----------------
__global__ void finalize_kernel(const float* __restrict__ partial, const float* __restrict__ gates,
                                const float* __restrict__ b2, float* __restrict__ out, int nt) {
    __shared__ float gs[50];
    const int n = blockIdx.x;
    const int t = threadIdx.x; // 256
    if (t < 50) gs[t] = gates[(size_t)n * 50 + t];
    __syncthreads();
    const size_t base = (size_t)n * 1024;
    const size_t st = (size_t)nt * 1024;
#pragma unroll
    for (int i = 0; i < 4; i++) {
        int d = t + i * 256;
        float v = partial[base + d] + partial[st + base + d]
                + partial[2 * st + base + d] + partial[3 * st + base + d];
#pragma unroll 10
        for (int e2 = 0; e2 < 50; e2++) v += gs[e2] * b2[e2 * 1024 + d];
        out[base + d] = v;
    }
}

extern "C" void kernel_launch(void* const* d_in, const int* in_sizes, int n_in,
                              void* d_out, int out_size, void* d_ws, size_t ws_size,
                              hipStream_t stream) {
    const float* x  = (const float*)d_in[0];
    const float* W1 = (const float*)d_in[1];
    const float* b1 = (const float*)d_in[2];
    const float* W2 = (const float*)d_in[3];
    const float* b2 = (const float*)d_in[4];
    const float* Wg = (const float*)d_in[5];
    const float* bg = (const float*)d_in[6];
    float* out = (float*)d_out;
    const int nt = in_sizes[0] / 1024; // 4096

    char* w = (char*)d_ws;
    auto carve = [&](size_t bytes) -> char* {
        char* p = w; w += (bytes + 255) & ~(size_t)255; return p;
    };
    float* gates   = (float*)carve((size_t)nt * 50 * 4);
    float* partial = (float*)carve((size_t)4 * nt * 1024 * 4);
    u16*   xb      = (u16*)carve((size_t)nt * 1024 * 2);
    const size_t fixed = (size_t)(w - (char*)d_ws);

    int eg = 1;
    const int cand[6] = {50, 25, 10, 5, 2, 1};
    for (int i = 0; i < 6; i++) {
        size_t need = fixed + (size_t)cand[i] * ((size_t)2 * 2097152 + (size_t)nt * 1024 * 2) + 4096;
        if (need <= ws_size) { eg = cand[i]; break; }
    }
    u16* Wt1 = (u16*)carve((size_t)eg * 1048576 * 2);
    u16* Wt2 = (u16*)carve((size_t)eg * 1048576 * 2);
    u16* Hp  = (u16*)carve((size_t)eg * nt * 1024 * 2);

    convert_x_kernel<<<(nt * 1024 / 8 + 255) / 256, 256, 0, stream>>>(x, xb, nt * 1024 / 8);
    gate_kernel<<<nt, 64, 0, stream>>>(x, Wg, bg, gates, nt);

    const int groups = 50 / eg;
    for (int g = 0; g < groups; ++g) {
        transpose_kernel<<<dim3(16, 16, 2 * eg), 256, 0, stream>>>(
            W1 + ((size_t)(g * eg) << 20), W2 + ((size_t)(g * eg) << 20), Wt1, Wt2, eg);
        gemm1_kernel<<<dim3(4, nt / 256, eg), 512, 0, stream>>>(
            xb, Wt1, b1 + (size_t)g * eg * 1024, gates, Hp, nt, g * eg);
        gemm2_kernel<<<dim3(4, nt / 256, 4), 512, 0, stream>>>(
            Hp, Wt2, partial, nt, eg, g == 0 ? 1 : 0);
    }
    finalize_kernel<<<nt, 256, 0, stream>>>(partial, gates, b2, out, nt);
}

// Round 2
// 1389.349 us; speedup vs baseline: 1.1698x; 1.0235x over previous
//
#include <hip/hip_runtime.h>
#include <stdint.h>

#define AS1 __attribute__((address_space(1)))
#define AS3 __attribute__((address_space(3)))

typedef unsigned short u16;
typedef __attribute__((ext_vector_type(8))) short s16x8;
typedef __attribute__((ext_vector_type(8))) unsigned short u16x8;
typedef __attribute__((ext_vector_type(4))) float f32x4;

__device__ __forceinline__ u16 f2bf(float f) {
    union { float f; unsigned int u; } v; v.f = f;
    unsigned int r = v.u + 0x7fffu + ((v.u >> 16) & 1u);
    return (u16)(r >> 16);
}

// async global->LDS, 16B per lane. LDS dest = wave-uniform base + lane*16.
__device__ __forceinline__ void gld_lds16(const u16* g, u16* l) {
    __builtin_amdgcn_global_load_lds((AS1 unsigned int*)(uintptr_t)g,
                                     (AS3 unsigned int*)(uintptr_t)l, 16, 0, 0);
}

// ---------------- convert x: fp32 -> bf16 ----------------
__global__ void convert_x_kernel(const float* __restrict__ X, u16* __restrict__ Xb, int total8) {
    int i = blockIdx.x * 256 + threadIdx.x;
    if (i < total8) {
        f32x4 a = ((const f32x4*)X)[2 * i];
        f32x4 b = ((const f32x4*)X)[2 * i + 1];
        u16x8 o;
#pragma unroll
        for (int j = 0; j < 4; j++) { o[j] = f2bf(a[j]); o[4 + j] = f2bf(b[j]); }
        ((u16x8*)Xb)[i] = o;
    }
}

// ---------------- gating: gates[n][50] = softmax(x@Wg + bg), all fp32 ----------------
__global__ void gate_kernel(const float* __restrict__ X, const float* __restrict__ Wg,
                            const float* __restrict__ bg, float* __restrict__ gates, int nt) {
    __shared__ float xs[1024];
    const int n = blockIdx.x;
    const int t = threadIdx.x; // 64 threads = 1 wave
#pragma unroll
    for (int i = 0; i < 16; i++) xs[t + i * 64] = X[(size_t)n * 1024 + t + i * 64];
    __syncthreads();
    float a = -INFINITY;
    if (t < 50) {
        float s0 = 0.f, s1 = 0.f, s2 = 0.f, s3 = 0.f;
        for (int d = 0; d < 1024; d += 4) {
            s0 += xs[d + 0] * Wg[(d + 0) * 50 + t];
            s1 += xs[d + 1] * Wg[(d + 1) * 50 + t];
            s2 += xs[d + 2] * Wg[(d + 2) * 50 + t];
            s3 += xs[d + 3] * Wg[(d + 3) * 50 + t];
        }
        a = (s0 + s1) + (s2 + s3) + bg[t];
    }
    float m = a;
#pragma unroll
    for (int off = 32; off > 0; off >>= 1) m = fmaxf(m, __shfl_xor(m, off));
    float p = (t < 50) ? __expf(a - m) : 0.f;
    float ss = p;
#pragma unroll
    for (int off = 32; off > 0; off >>= 1) ss += __shfl_xor(ss, off);
    if (t < 50) gates[(size_t)n * 50 + t] = p / ss;
}

// ------- transpose+convert 1024x1024 fp32 [k][n] -> bf16 [n][k]; z: eg W1 mats then eg W2 mats ----
__global__ void transpose_kernel(const float* __restrict__ W1s, const float* __restrict__ W2s,
                                 u16* __restrict__ Wt1, u16* __restrict__ Wt2, int eg) {
    __shared__ u16 tile[64 * 65];
    const int t = threadIdx.x; // 256
    const int z = blockIdx.z;
    const float* src; u16* dst;
    if (z < eg) { src = W1s + ((size_t)z << 20); dst = Wt1 + ((size_t)z << 20); }
    else        { src = W2s + ((size_t)(z - eg) << 20); dst = Wt2 + ((size_t)(z - eg) << 20); }
    const int k0 = blockIdx.y * 64;
    const int n0 = blockIdx.x * 64;
#pragma unroll
    for (int p = 0; p < 4; p++) {
        int r = (t >> 4) + 16 * p;
        int c = t & 15;
        f32x4 v = *(const f32x4*)(src + (size_t)(k0 + r) * 1024 + n0 + c * 4);
#pragma unroll
        for (int j = 0; j < 4; j++) tile[r * 65 + c * 4 + j] = f2bf(v[j]);
    }
    __syncthreads();
#pragma unroll
    for (int p = 0; p < 2; p++) {
        int h = (t >> 3) + 32 * p;
        int c = t & 7;
        u16x8 o;
#pragma unroll
        for (int j = 0; j < 8; j++) o[j] = tile[(c * 8 + j) * 65 + h];
        *(u16x8*)(dst + (size_t)(n0 + h) * 1024 + k0 + c * 8) = o;
    }
}

// =====================================================================================
// 256x256-tile pipelined GEMMs: BK=32, 4 LDS buffers, prefetch distance 3,
// counted vmcnt (8 -> 4 -> 0), one s_barrier per K-tile, setprio around MFMA cluster.
// 8 waves (512 thr), wave grid 2m x 4n, per-wave output 128x64 (acc 8x4 f32x4).
// LDS swizzle: both-sides XOR (pre-swizzled global source + XOR'd ds_read offset).
// BK=32 rows are 64B (16 banks), so the XOR must pair rows to cover all 32 banks:
// chunk = fq ^ ((row>>1)&3). Within 16 fragment rows this yields 8 distinct 16B
// slots (row-parity x 4 chunks) x 2 lanes = 2-way = free. (row&3) was 4-way: 3.9e7
// conflict cycles measured in R1.
// =====================================================================================

#define BUF_U16 16384  // per buffer: A 8192 u16 (256x32) + B 8192 u16 (256x32) = 32KB

#define STG1(t) { int bo = ((t) & 3) * BUF_U16;                                   \
        const u16* a = Ag + (t) * 32; const u16* b = Bg + (t) * 32;               \
        gld_lds16(a, Ald + bo);          gld_lds16(a + 131072, Ald + bo + 4096);  \
        gld_lds16(b, Bld + bo);          gld_lds16(b + 131072, Bld + bo + 4096); }

#define STG2(t) { int kt = kb + (t) * 32; int ee = kt >> 10; int kk = kt & 1023;  \
        const u16* a = Agr + (size_t)ee * ntk + kk;                               \
        const u16* b = Bgr + ((size_t)ee << 20) + kk;                             \
        int bo = ((t) & 3) * BUF_U16;                                             \
        gld_lds16(a, Ald + bo);          gld_lds16(a + 131072, Ald + bo + 4096);  \
        gld_lds16(b, Bld + bo);          gld_lds16(b + 131072, Bld + bo + 4096); }

#define MMSTEP(t, VM, DO, STG) {                                                  \
        asm volatile("s_waitcnt vmcnt(" VM ")\n\ts_barrier" ::: "memory");        \
        if (DO) STG((t) + 3);                                                     \
        const u16* bp = smem + ((t) & 3) * BUF_U16;                               \
        s16x8 av[8], bv[4];                                                       \
        _Pragma("unroll") for (int mi = 0; mi < 8; mi++)                          \
            av[mi] = *(const s16x8*)(bp + aoff[mi]);                              \
        _Pragma("unroll") for (int nj = 0; nj < 4; nj++)                          \
            bv[nj] = *(const s16x8*)(bp + boff[nj]);                              \
        __builtin_amdgcn_s_setprio(1);                                            \
        _Pragma("unroll") for (int mi = 0; mi < 8; mi++)                          \
        _Pragma("unroll") for (int nj = 0; nj < 4; nj++)                          \
            acc[mi * 4 + nj] = __builtin_amdgcn_mfma_f32_16x16x32_bf16(           \
                av[mi], bv[nj], acc[mi * 4 + nj], 0, 0, 0);                       \
        __builtin_amdgcn_s_setprio(0); }

// ---------------- gemm1: Hp[e] = bf16( gates[:,e] * relu(Xb @ W1t[e] + b1[e]) ) ----------
__global__ __launch_bounds__(512, 2)
void gemm1_kernel(const u16* __restrict__ X, const u16* __restrict__ Wt1,
                  const float* __restrict__ b1, const float* __restrict__ gates,
                  u16* __restrict__ Hp, int nt, int egbase) {
    __shared__ __align__(16) u16 smem[67584]; // 4 bufs (128KB) / C-tile 256x264 (135KB)
    const int tid = threadIdx.x, wave = tid >> 6, lane = tid & 63;
    const int e = blockIdx.z;
    const int n0 = blockIdx.x * 256, m0 = blockIdx.y * 256;

    // staging: thread covers row srow (call0) / srow+128 (call1), 16B chunk, pre-swizzled source
    const int srow = wave * 16 + (lane >> 2);
    const int scg = ((lane & 3) ^ ((srow >> 1) & 3)) * 8;
    const u16* Ag = X + (size_t)(m0 + srow) * 1024 + scg;
    const u16* Bg = Wt1 + ((size_t)e << 20) + (size_t)(n0 + srow) * 1024 + scg;
    u16* Ald = smem + wave * 512;
    u16* Bld = smem + 8192 + wave * 512;

    const int wm = wave >> 2, wn = wave & 3;
    const int fr = lane & 15, fq = lane >> 4;
    int aoff[8], boff[4];
#pragma unroll
    for (int mi = 0; mi < 8; mi++) {
        int ra = wm * 128 + mi * 16 + fr;
        aoff[mi] = ra * 32 + ((fq ^ ((ra >> 1) & 3)) * 8);
    }
#pragma unroll
    for (int nj = 0; nj < 4; nj++) {
        int rb = wn * 64 + nj * 16 + fr;
        boff[nj] = 8192 + rb * 32 + ((fq ^ ((rb >> 1) & 3)) * 8);
    }

    f32x4 acc[32];
#pragma unroll
    for (int i = 0; i < 32; i++) acc[i] = (f32x4){0.f, 0.f, 0.f, 0.f};

    STG1(0); STG1(1); STG1(2);
    for (int t = 0; t < 29; ++t) MMSTEP(t, "8", 1, STG1);
    MMSTEP(29, "8", 0, STG1);
    MMSTEP(30, "4", 0, STG1);
    MMSTEP(31, "0", 0, STG1);

    // epilogue: bias + relu + gate, bounce through LDS for coalesced bf16 stores
    const float* b1e = b1 + (size_t)e * 1024;
    float b1v[4];
#pragma unroll
    for (int nj = 0; nj < 4; nj++) b1v[nj] = b1e[n0 + wn * 64 + nj * 16 + fr];
    const int eglob = egbase + e;

    __syncthreads(); // all waves done reading bufs; reuse smem as C tile (stride 264)
#pragma unroll
    for (int mi = 0; mi < 8; mi++) {
#pragma unroll
        for (int ri = 0; ri < 4; ri++) {
            int row = wm * 128 + mi * 16 + fq * 4 + ri;
            float g = gates[(size_t)(m0 + row) * 50 + eglob];
#pragma unroll
            for (int nj = 0; nj < 4; nj++) {
                int col = wn * 64 + nj * 16 + fr;
                float h = acc[mi * 4 + nj][ri] + b1v[nj];
                h = h > 0.f ? h * g : 0.f;
                smem[row * 264 + col] = f2bf(h);
            }
        }
    }
    __syncthreads();
    u16* HpE = Hp + (size_t)e * nt * 1024;
    const int c = tid & 31, rr = tid >> 5;
#pragma unroll
    for (int p = 0; p < 16; p++) {
        int r = rr + p * 16;
        u16x8 v = *(const u16x8*)(smem + r * 264 + c * 8);
        *(u16x8*)(HpE + (size_t)(m0 + r) * 1024 + n0 + c * 8) = v;
    }
}

// ---------------- gemm2: partial[s] (+)= slice_s( sum_e Hp[e] @ W2t[e] ), s in 0..3 ----------
__global__ __launch_bounds__(512, 2)
void gemm2_kernel(const u16* __restrict__ Hp, const u16* __restrict__ Wt2,
                  float* __restrict__ partial, int nt, int eg, int init) {
    __shared__ __align__(16) u16 smem[65536]; // 4 bufs = 128KB
    const int tid = threadIdx.x, wave = tid >> 6, lane = tid & 63;
    const int s = blockIdx.z;
    const int n0 = blockIdx.x * 256, m0 = blockIdx.y * 256;

    const int srow = wave * 16 + (lane >> 2);
    const int scg = ((lane & 3) ^ ((srow >> 1) & 3)) * 8;
    const u16* Agr = Hp + (size_t)(m0 + srow) * 1024 + scg;
    const u16* Bgr = Wt2 + (size_t)(n0 + srow) * 1024 + scg;
    const size_t ntk = (size_t)nt * 1024;
    u16* Ald = smem + wave * 512;
    u16* Bld = smem + 8192 + wave * 512;

    const int wm = wave >> 2, wn = wave & 3;
    const int fr = lane & 15, fq = lane >> 4;
    int aoff[8], boff[4];
#pragma unroll
    for (int mi = 0; mi < 8; mi++) {
        int ra = wm * 128 + mi * 16 + fr;
        aoff[mi] = ra * 32 + ((fq ^ ((ra >> 1) & 3)) * 8);
    }
#pragma unroll
    for (int nj = 0; nj < 4; nj++) {
        int rb = wn * 64 + nj * 16 + fr;
        boff[nj] = 8192 + rb * 32 + ((fq ^ ((rb >> 1) & 3)) * 8);
    }

    f32x4 acc[32];
#pragma unroll
    for (int i = 0; i < 32; i++) acc[i] = (f32x4){0.f, 0.f, 0.f, 0.f};

    const int NT = eg * 8;       // K-tiles of 32 in this slice (eg*1024/4/32)
    const int kb = s * NT * 32;  // absolute k start of slice

    STG2(0); STG2(1); STG2(2);
    for (int t = 0; t < NT - 3; ++t) MMSTEP(t, "8", 1, STG2);
    MMSTEP(NT - 3, "8", 0, STG2);
    MMSTEP(NT - 2, "4", 0, STG2);
    MMSTEP(NT - 1, "0", 0, STG2);

    float* pp = partial + (size_t)s * nt * 1024;
#pragma unroll
    for (int mi = 0; mi < 8; mi++) {
#pragma unroll
        for (int ri = 0; ri < 4; ri++) {
            int gr = m0 + wm * 128 + mi * 16 + fq * 4 + ri;
#pragma unroll
            for (int nj = 0; nj < 4; nj++) {
                size_t idx = (size_t)gr * 1024 + n0 + wn * 64 + nj * 16 + fr;
                float v = acc[mi * 4 + nj][ri];
                if (!init) v += pp[idx];
                pp[idx] = v;
            }
        }
    }
}

// ---------------- finalize: out = sum_s partial[s] + sum_e gates*b2, fp32 out ----------------
__global__ void finalize_kernel(const float* __restrict__ partial, const float* __restrict__ gates,
                                const float* __restrict__ b2, float* __restrict__ out, int nt) {
    __shared__ float gs[50];
    const int n = blockIdx.x;
    const int t = threadIdx.x; // 256
    if (t < 50) gs[t] = gates[(size_t)n * 50 + t];
    __syncthreads();
    const size_t base = (size_t)n * 1024;
    const size_t st = (size_t)nt * 1024;
#pragma unroll
    for (int i = 0; i < 4; i++) {
        int d = t + i * 256;
        float v = partial[base + d] + partial[st + base + d]
                + partial[2 * st + base + d] + partial[3 * st + base + d];
#pragma unroll 10
        for (int e2 = 0; e2 < 50; e2++) v += gs[e2] * b2[e2 * 1024 + d];
        out[base + d] = v;
    }
}

extern "C" void kernel_launch(void* const* d_in, const int* in_sizes, int n_in,
                              void* d_out, int out_size, void* d_ws, size_t ws_size,
                              hipStream_t stream) {
    const float* x  = (const float*)d_in[0];
    const float* W1 = (const float*)d_in[1];
    const float* b1 = (const float*)d_in[2];
    const float* W2 = (const float*)d_in[3];
    const float* b2 = (const float*)d_in[4];
    const float* Wg = (const float*)d_in[5];
    const float* bg = (const float*)d_in[6];
    float* out = (float*)d_out;
    const int nt = in_sizes[0] / 1024; // 4096

    char* w = (char*)d_ws;
    auto carve = [&](size_t bytes) -> char* {
        char* p = w; w += (bytes + 255) & ~(size_t)255; return p;
    };
    float* gates   = (float*)carve((size_t)nt * 50 * 4);
    float* partial = (float*)carve((size_t)4 * nt * 1024 * 4);
    u16*   xb      = (u16*)carve((size_t)nt * 1024 * 2);
    const size_t fixed = (size_t)(w - (char*)d_ws);

    int eg = 1;
    const int cand[6] = {50, 25, 10, 5, 2, 1};
    for (int i = 0; i < 6; i++) {
        size_t need = fixed + (size_t)cand[i] * ((size_t)2 * 2097152 + (size_t)nt * 1024 * 2) + 4096;
        if (need <= ws_size) { eg = cand[i]; break; }
    }
    u16* Wt1 = (u16*)carve((size_t)eg * 1048576 * 2);
    u16* Wt2 = (u16*)carve((size_t)eg * 1048576 * 2);
    u16* Hp  = (u16*)carve((size_t)eg * nt * 1024 * 2);

    convert_x_kernel<<<(nt * 1024 / 8 + 255) / 256, 256, 0, stream>>>(x, xb, nt * 1024 / 8);
    gate_kernel<<<nt, 64, 0, stream>>>(x, Wg, bg, gates, nt);

    const int groups = 50 / eg;
    for (int g = 0; g < groups; ++g) {
        transpose_kernel<<<dim3(16, 16, 2 * eg), 256, 0, stream>>>(
            W1 + ((size_t)(g * eg) << 20), W2 + ((size_t)(g * eg) << 20), Wt1, Wt2, eg);
        gemm1_kernel<<<dim3(4, nt / 256, eg), 512, 0, stream>>>(
            xb, Wt1, b1 + (size_t)g * eg * 1024, gates, Hp, nt, g * eg);
        gemm2_kernel<<<dim3(4, nt / 256, 4), 512, 0, stream>>>(
            Hp, Wt2, partial, nt, eg, g == 0 ? 1 : 0);
    }
    finalize_kernel<<<nt, 256, 0, stream>>>(partial, gates, b2, out, nt);
}

// Round 4
// 1381.240 us; speedup vs baseline: 1.1766x; 1.0059x over previous
//
#include <hip/hip_runtime.h>
#include <stdint.h>

#define AS1 __attribute__((address_space(1)))
#define AS3 __attribute__((address_space(3)))

typedef unsigned short u16;
typedef __attribute__((ext_vector_type(8))) short s16x8;
typedef __attribute__((ext_vector_type(8))) unsigned short u16x8;
typedef __attribute__((ext_vector_type(4))) float f32x4;

__device__ __forceinline__ u16 f2bf(float f) {
    union { float f; unsigned int u; } v; v.f = f;
    unsigned int r = v.u + 0x7fffu + ((v.u >> 16) & 1u);
    return (u16)(r >> 16);
}

// async global->LDS, 16B per lane. LDS dest = wave-uniform base + lane*16.
__device__ __forceinline__ void gld_lds16(const u16* g, u16* l) {
    __builtin_amdgcn_global_load_lds((AS1 unsigned int*)(uintptr_t)g,
                                     (AS3 unsigned int*)(uintptr_t)l, 16, 0, 0);
}

// ---------------- convert x: fp32 -> bf16 ----------------
__global__ void convert_x_kernel(const float* __restrict__ X, u16* __restrict__ Xb, int total8) {
    int i = blockIdx.x * 256 + threadIdx.x;
    if (i < total8) {
        f32x4 a = ((const f32x4*)X)[2 * i];
        f32x4 b = ((const f32x4*)X)[2 * i + 1];
        u16x8 o;
#pragma unroll
        for (int j = 0; j < 4; j++) { o[j] = f2bf(a[j]); o[4 + j] = f2bf(b[j]); }
        ((u16x8*)Xb)[i] = o;
    }
}

// ---------------- gating: gates[n][50] = softmax(x@Wg + bg), all fp32 ----------------
__global__ void gate_kernel(const float* __restrict__ X, const float* __restrict__ Wg,
                            const float* __restrict__ bg, float* __restrict__ gates, int nt) {
    __shared__ float xs[1024];
    const int n = blockIdx.x;
    const int t = threadIdx.x; // 64 threads = 1 wave
#pragma unroll
    for (int i = 0; i < 16; i++) xs[t + i * 64] = X[(size_t)n * 1024 + t + i * 64];
    __syncthreads();
    float a = -INFINITY;
    if (t < 50) {
        float s0 = 0.f, s1 = 0.f, s2 = 0.f, s3 = 0.f;
        for (int d = 0; d < 1024; d += 4) {
            s0 += xs[d + 0] * Wg[(d + 0) * 50 + t];
            s1 += xs[d + 1] * Wg[(d + 1) * 50 + t];
            s2 += xs[d + 2] * Wg[(d + 2) * 50 + t];
            s3 += xs[d + 3] * Wg[(d + 3) * 50 + t];
        }
        a = (s0 + s1) + (s2 + s3) + bg[t];
    }
    float m = a;
#pragma unroll
    for (int off = 32; off > 0; off >>= 1) m = fmaxf(m, __shfl_xor(m, off));
    float p = (t < 50) ? __expf(a - m) : 0.f;
    float ss = p;
#pragma unroll
    for (int off = 32; off > 0; off >>= 1) ss += __shfl_xor(ss, off);
    if (t < 50) gates[(size_t)n * 50 + t] = p / ss;
}

// ------- transpose+convert 1024x1024 fp32 [k][n] -> bf16 [n][k]; z: eg W1 mats then eg W2 mats ----
__global__ void transpose_kernel(const float* __restrict__ W1s, const float* __restrict__ W2s,
                                 u16* __restrict__ Wt1, u16* __restrict__ Wt2, int eg) {
    __shared__ u16 tile[64 * 65];
    const int t = threadIdx.x; // 256
    const int z = blockIdx.z;
    const float* src; u16* dst;
    if (z < eg) { src = W1s + ((size_t)z << 20); dst = Wt1 + ((size_t)z << 20); }
    else        { src = W2s + ((size_t)(z - eg) << 20); dst = Wt2 + ((size_t)(z - eg) << 20); }
    const int k0 = blockIdx.y * 64;
    const int n0 = blockIdx.x * 64;
#pragma unroll
    for (int p = 0; p < 4; p++) {
        int r = (t >> 4) + 16 * p;
        int c = t & 15;
        f32x4 v = *(const f32x4*)(src + (size_t)(k0 + r) * 1024 + n0 + c * 4);
#pragma unroll
        for (int j = 0; j < 4; j++) tile[r * 65 + c * 4 + j] = f2bf(v[j]);
    }
    __syncthreads();
#pragma unroll
    for (int p = 0; p < 2; p++) {
        int h = (t >> 3) + 32 * p;
        int c = t & 7;
        u16x8 o;
#pragma unroll
        for (int j = 0; j < 8; j++) o[j] = tile[(c * 8 + j) * 65 + h];
        *(u16x8*)(dst + (size_t)(n0 + h) * 1024 + k0 + c * 8) = o;
    }
}

// =====================================================================================
// 256x256-tile pipelined GEMMs: BK=32, 4 LDS buffers, prefetch distance 3,
// counted vmcnt (8 -> 4 -> 0), setprio around MFMA clusters.
// 8 waves (512 thr), wave grid 2m x 4n, per-wave output 128x64 (acc 8x4 f32x4).
// Each K-tile is split into TWO phases (T3 fine interleave):
//   {vmcnt(8); bar; stage A-half; read av0-3,bv; prio1; 16 MFMA; prio0;
//    stage B-half; read av4-7; bar; prio1; 16 MFMA; prio0}
// Between barriers each wave mixes gld/ds_read/MFMA, so wave X's MFMA overlaps
// wave Y's LDS burst instead of CU-wide burst serialization (R1: MfmaUtil 39%,
// ~1.1k cyc/tile of serialized ds_read next to 1.24k cyc of MFMA).
// LDS swizzle (R1-verified, 0 conflicts): chunk = fq ^ ((row>>1)&3), both sides.
// =====================================================================================

#define BUF_U16 16384  // per buffer: A 8192 u16 (256x32) + B 8192 u16 (256x32) = 32KB

#define STG1A(t) { int bo = ((t) & 3) * BUF_U16;                                  \
        const u16* a = Ag + (t) * 32;                                             \
        gld_lds16(a, Ald + bo);          gld_lds16(a + 131072, Ald + bo + 4096); }
#define STG1B(t) { int bo = ((t) & 3) * BUF_U16;                                  \
        const u16* b = Bg + (t) * 32;                                             \
        gld_lds16(b, Bld + bo);          gld_lds16(b + 131072, Bld + bo + 4096); }

#define STG2A(t) { int kt = kb + (t) * 32; int ee = kt >> 10; int kk = kt & 1023; \
        const u16* a = Agr + (size_t)ee * ntk + kk;                               \
        int bo = ((t) & 3) * BUF_U16;                                             \
        gld_lds16(a, Ald + bo);          gld_lds16(a + 131072, Ald + bo + 4096); }
#define STG2B(t) { int kt = kb + (t) * 32; int ee = kt >> 10; int kk = kt & 1023; \
        const u16* b = Bgr + ((size_t)ee << 20) + kk;                             \
        int bo = ((t) & 3) * BUF_U16;                                             \
        gld_lds16(b, Bld + bo);          gld_lds16(b + 131072, Bld + bo + 4096); }

#define MMSTEP(t, VM, DO, STGA, STGB) {                                           \
        asm volatile("s_waitcnt vmcnt(" VM ")\n\ts_barrier" ::: "memory");        \
        if (DO) STGA((t) + 3);                                                    \
        const u16* bp = smem + ((t) & 3) * BUF_U16;                               \
        s16x8 av0[4], av1[4], bv[4];                                              \
        _Pragma("unroll") for (int mi = 0; mi < 4; mi++)                          \
            av0[mi] = *(const s16x8*)(bp + aoff[mi]);                             \
        _Pragma("unroll") for (int nj = 0; nj < 4; nj++)                          \
            bv[nj] = *(const s16x8*)(bp + boff[nj]);                              \
        __builtin_amdgcn_s_setprio(1);                                            \
        _Pragma("unroll") for (int mi = 0; mi < 4; mi++)                          \
        _Pragma("unroll") for (int nj = 0; nj < 4; nj++)                          \
            acc[mi * 4 + nj] = __builtin_amdgcn_mfma_f32_16x16x32_bf16(           \
                av0[mi], bv[nj], acc[mi * 4 + nj], 0, 0, 0);                      \
        __builtin_amdgcn_s_setprio(0);                                            \
        if (DO) STGB((t) + 3);                                                    \
        _Pragma("unroll") for (int mi = 0; mi < 4; mi++)                          \
            av1[mi] = *(const s16x8*)(bp + aoff[4 + mi]);                         \
        __builtin_amdgcn_s_barrier();                                             \
        __builtin_amdgcn_s_setprio(1);                                            \
        _Pragma("unroll") for (int mi = 0; mi < 4; mi++)                          \
        _Pragma("unroll") for (int nj = 0; nj < 4; nj++)                          \
            acc[16 + mi * 4 + nj] = __builtin_amdgcn_mfma_f32_16x16x32_bf16(      \
                av1[mi], bv[nj], acc[16 + mi * 4 + nj], 0, 0, 0);                 \
        __builtin_amdgcn_s_setprio(0); }

// ---------------- gemm1: Hp[e] = bf16( gates[:,e] * relu(Xb @ W1t[e] + b1[e]) ) ----------
__global__ __launch_bounds__(512, 2)
void gemm1_kernel(const u16* __restrict__ X, const u16* __restrict__ Wt1,
                  const float* __restrict__ b1, const float* __restrict__ gates,
                  u16* __restrict__ Hp, int nt, int egbase) {
    __shared__ __align__(16) u16 smem[67584]; // 4 bufs (128KB) / C-tile 256x264 (135KB)
    const int tid = threadIdx.x, wave = tid >> 6, lane = tid & 63;
    const int e = blockIdx.z;
    const int n0 = blockIdx.x * 256, m0 = blockIdx.y * 256;

    // staging: thread covers row srow (call0) / srow+128 (call1), 16B chunk, pre-swizzled source
    const int srow = wave * 16 + (lane >> 2);
    const int scg = ((lane & 3) ^ ((srow >> 1) & 3)) * 8;
    const u16* Ag = X + (size_t)(m0 + srow) * 1024 + scg;
    const u16* Bg = Wt1 + ((size_t)e << 20) + (size_t)(n0 + srow) * 1024 + scg;
    u16* Ald = smem + wave * 512;
    u16* Bld = smem + 8192 + wave * 512;

    const int wm = wave >> 2, wn = wave & 3;
    const int fr = lane & 15, fq = lane >> 4;
    int aoff[8], boff[4];
#pragma unroll
    for (int mi = 0; mi < 8; mi++) {
        int ra = wm * 128 + mi * 16 + fr;
        aoff[mi] = ra * 32 + ((fq ^ ((ra >> 1) & 3)) * 8);
    }
#pragma unroll
    for (int nj = 0; nj < 4; nj++) {
        int rb = wn * 64 + nj * 16 + fr;
        boff[nj] = 8192 + rb * 32 + ((fq ^ ((rb >> 1) & 3)) * 8);
    }

    f32x4 acc[32];
#pragma unroll
    for (int i = 0; i < 32; i++) acc[i] = (f32x4){0.f, 0.f, 0.f, 0.f};

    STG1A(0); STG1B(0); STG1A(1); STG1B(1); STG1A(2); STG1B(2);
    for (int t = 0; t < 29; ++t) MMSTEP(t, "8", 1, STG1A, STG1B);
    MMSTEP(29, "8", 0, STG1A, STG1B);
    MMSTEP(30, "4", 0, STG1A, STG1B);
    MMSTEP(31, "0", 0, STG1A, STG1B);

    // epilogue: bias + relu + gate, bounce through LDS for coalesced bf16 stores
    const float* b1e = b1 + (size_t)e * 1024;
    float b1v[4];
#pragma unroll
    for (int nj = 0; nj < 4; nj++) b1v[nj] = b1e[n0 + wn * 64 + nj * 16 + fr];
    const int eglob = egbase + e;

    __syncthreads(); // all waves done reading bufs; reuse smem as C tile (stride 264)
#pragma unroll
    for (int mi = 0; mi < 8; mi++) {
#pragma unroll
        for (int ri = 0; ri < 4; ri++) {
            int row = wm * 128 + mi * 16 + fq * 4 + ri;
            float g = gates[(size_t)(m0 + row) * 50 + eglob];
#pragma unroll
            for (int nj = 0; nj < 4; nj++) {
                int col = wn * 64 + nj * 16 + fr;
                float h = acc[mi * 4 + nj][ri] + b1v[nj];
                h = h > 0.f ? h * g : 0.f;
                smem[row * 264 + col] = f2bf(h);
            }
        }
    }
    __syncthreads();
    u16* HpE = Hp + (size_t)e * nt * 1024;
    const int c = tid & 31, rr = tid >> 5;
#pragma unroll
    for (int p = 0; p < 16; p++) {
        int r = rr + p * 16;
        u16x8 v = *(const u16x8*)(smem + r * 264 + c * 8);
        *(u16x8*)(HpE + (size_t)(m0 + r) * 1024 + n0 + c * 8) = v;
    }
}

// ---------------- gemm2: partial[s] (+)= slice_s( sum_e Hp[e] @ W2t[e] ), s in 0..3 ----------
__global__ __launch_bounds__(512, 2)
void gemm2_kernel(const u16* __restrict__ Hp, const u16* __restrict__ Wt2,
                  float* __restrict__ partial, int nt, int eg, int init) {
    __shared__ __align__(16) u16 smem[65536]; // 4 bufs = 128KB
    const int tid = threadIdx.x, wave = tid >> 6, lane = tid & 63;
    const int s = blockIdx.z;
    const int n0 = blockIdx.x * 256, m0 = blockIdx.y * 256;

    const int srow = wave * 16 + (lane >> 2);
    const int scg = ((lane & 3) ^ ((srow >> 1) & 3)) * 8;
    const u16* Agr = Hp + (size_t)(m0 + srow) * 1024 + scg;
    const u16* Bgr = Wt2 + (size_t)(n0 + srow) * 1024 + scg;
    const size_t ntk = (size_t)nt * 1024;
    u16* Ald = smem + wave * 512;
    u16* Bld = smem + 8192 + wave * 512;

    const int wm = wave >> 2, wn = wave & 3;
    const int fr = lane & 15, fq = lane >> 4;
    int aoff[8], boff[4];
#pragma unroll
    for (int mi = 0; mi < 8; mi++) {
        int ra = wm * 128 + mi * 16 + fr;
        aoff[mi] = ra * 32 + ((fq ^ ((ra >> 1) & 3)) * 8);
    }
#pragma unroll
    for (int nj = 0; nj < 4; nj++) {
        int rb = wn * 64 + nj * 16 + fr;
        boff[nj] = 8192 + rb * 32 + ((fq ^ ((rb >> 1) & 3)) * 8);
    }

    f32x4 acc[32];
#pragma unroll
    for (int i = 0; i < 32; i++) acc[i] = (f32x4){0.f, 0.f, 0.f, 0.f};

    const int NT = eg * 8;       // K-tiles of 32 in this slice (eg*1024/4/32)
    const int kb = s * NT * 32;  // absolute k start of slice

    STG2A(0); STG2B(0); STG2A(1); STG2B(1); STG2A(2); STG2B(2);
    for (int t = 0; t < NT - 3; ++t) MMSTEP(t, "8", 1, STG2A, STG2B);
    MMSTEP(NT - 3, "8", 0, STG2A, STG2B);
    MMSTEP(NT - 2, "4", 0, STG2A, STG2B);
    MMSTEP(NT - 1, "0", 0, STG2A, STG2B);

    float* pp = partial + (size_t)s * nt * 1024;
#pragma unroll
    for (int mi = 0; mi < 8; mi++) {
#pragma unroll
        for (int ri = 0; ri < 4; ri++) {
            int gr = m0 + wm * 128 + mi * 16 + fq * 4 + ri;
#pragma unroll
            for (int nj = 0; nj < 4; nj++) {
                size_t idx = (size_t)gr * 1024 + n0 + wn * 64 + nj * 16 + fr;
                float v = acc[mi * 4 + nj][ri];
                if (!init) v += pp[idx];
                pp[idx] = v;
            }
        }
    }
}

// ---------------- finalize: out = sum_s partial[s] + sum_e gates*b2, fp32 out ----------------
__global__ void finalize_kernel(const float* __restrict__ partial, const float* __restrict__ gates,
                                const float* __restrict__ b2, float* __restrict__ out, int nt) {
    __shared__ float gs[50];
    const int n = blockIdx.x;
    const int t = threadIdx.x; // 256
    if (t < 50) gs[t] = gates[(size_t)n * 50 + t];
    __syncthreads();
    const size_t base = (size_t)n * 1024;
    const size_t st = (size_t)nt * 1024;
#pragma unroll
    for (int i = 0; i < 4; i++) {
        int d = t + i * 256;
        float v = partial[base + d] + partial[st + base + d]
                + partial[2 * st + base + d] + partial[3 * st + base + d];
#pragma unroll 10
        for (int e2 = 0; e2 < 50; e2++) v += gs[e2] * b2[e2 * 1024 + d];
        out[base + d] = v;
    }
}

extern "C" void kernel_launch(void* const* d_in, const int* in_sizes, int n_in,
                              void* d_out, int out_size, void* d_ws, size_t ws_size,
                              hipStream_t stream) {
    const float* x  = (const float*)d_in[0];
    const float* W1 = (const float*)d_in[1];
    const float* b1 = (const float*)d_in[2];
    const float* W2 = (const float*)d_in[3];
    const float* b2 = (const float*)d_in[4];
    const float* Wg = (const float*)d_in[5];
    const float* bg = (const float*)d_in[6];
    float* out = (float*)d_out;
    const int nt = in_sizes[0] / 1024; // 4096

    char* w = (char*)d_ws;
    auto carve = [&](size_t bytes) -> char* {
        char* p = w; w += (bytes + 255) & ~(size_t)255; return p;
    };
    float* gates   = (float*)carve((size_t)nt * 50 * 4);
    float* partial = (float*)carve((size_t)4 * nt * 1024 * 4);
    u16*   xb      = (u16*)carve((size_t)nt * 1024 * 2);
    const size_t fixed = (size_t)(w - (char*)d_ws);

    int eg = 1;
    const int cand[6] = {50, 25, 10, 5, 2, 1};
    for (int i = 0; i < 6; i++) {
        size_t need = fixed + (size_t)cand[i] * ((size_t)2 * 2097152 + (size_t)nt * 1024 * 2) + 4096;
        if (need <= ws_size) { eg = cand[i]; break; }
    }
    u16* Wt1 = (u16*)carve((size_t)eg * 1048576 * 2);
    u16* Wt2 = (u16*)carve((size_t)eg * 1048576 * 2);
    u16* Hp  = (u16*)carve((size_t)eg * nt * 1024 * 2);

    convert_x_kernel<<<(nt * 1024 / 8 + 255) / 256, 256, 0, stream>>>(x, xb, nt * 1024 / 8);
    gate_kernel<<<nt, 64, 0, stream>>>(x, Wg, bg, gates, nt);

    const int groups = 50 / eg;
    for (int g = 0; g < groups; ++g) {
        transpose_kernel<<<dim3(16, 16, 2 * eg), 256, 0, stream>>>(
            W1 + ((size_t)(g * eg) << 20), W2 + ((size_t)(g * eg) << 20), Wt1, Wt2, eg);
        gemm1_kernel<<<dim3(4, nt / 256, eg), 512, 0, stream>>>(
            xb, Wt1, b1 + (size_t)g * eg * 1024, gates, Hp, nt, g * eg);
        gemm2_kernel<<<dim3(4, nt / 256, 4), 512, 0, stream>>>(
            Hp, Wt2, partial, nt, eg, g == 0 ? 1 : 0);
    }
    finalize_kernel<<<nt, 256, 0, stream>>>(partial, gates, b2, out, nt);
}